// Round 4
// baseline (286.129 us; speedup 1.0000x reference)
//
#include <hip/hip_runtime.h>
#include <hip/hip_bf16.h>

// Problem constants
#define NB 4
#define NC 256
#define NN 4096   // H*W
// DQK = 32

typedef __bf16 bf16x8 __attribute__((ext_vector_type(8)));
typedef float f32x4 __attribute__((ext_vector_type(4)));
typedef float f32x16 __attribute__((ext_vector_type(16)));
typedef unsigned short u16x4 __attribute__((ext_vector_type(4)));
typedef unsigned short u16x8 __attribute__((ext_vector_type(8)));
typedef unsigned int u32x2 __attribute__((ext_vector_type(2)));
typedef unsigned int u32x4 __attribute__((ext_vector_type(4)));

#if __has_builtin(__builtin_amdgcn_exp2f)
#define EXP2(x) __builtin_amdgcn_exp2f(x)
#else
#define EXP2(x) exp2f(x)
#endif

#define LOG2E 1.4426950408889634f

__device__ __forceinline__ unsigned short f2bf(float f) {
  union { __bf16 h; unsigned short u; } v;
  v.h = (__bf16)f;               // native v_cvt (RNE) on gfx950
  return v.u;
}
__device__ __forceinline__ float bf2f(unsigned short h) {
  union { unsigned u; float f; } v; v.u = ((unsigned)h) << 16;
  return v.f;
}

// Exchange: x = [a(lanes0-31), a-from-cross... see k4 derivation.
// Sem (gfx950): D.row1 <-> S.row0:  x = [a.lo, b.lo_cross], y = [a.hi_cross, b.hi]
__device__ __forceinline__ u32x2 lane32swap(unsigned a, unsigned b) {
#if __has_builtin(__builtin_amdgcn_permlane32_swap)
  return __builtin_amdgcn_permlane32_swap(a, b, false, false);
#else
  unsigned ca = __shfl_xor(a, 32), cb = __shfl_xor(b, 32);
  int h = (threadIdx.x & 63) >> 5;
  u32x2 r; r[0] = h ? cb : a; r[1] = h ? b : ca;
  return r;
#endif
}

// ---------------------------------------------------------------------------
// K0: weights -> bf16 (Wcat = [Wq;Wk] 64x256, Wvb 256x256), zero stats buffer
__global__ __launch_bounds__(256) void k0_prep(const float* __restrict__ Wq,
                                               const float* __restrict__ Wk,
                                               const float* __restrict__ Wv,
                                               unsigned short* __restrict__ Wcat,
                                               unsigned short* __restrict__ Wvb,
                                               float* __restrict__ stats) {
  int tid = blockIdx.x * 256 + threadIdx.x;
  int nt = gridDim.x * 256;
  for (int i = tid; i < 64 * NC; i += nt) {
    int d = i >> 8, c = i & 255;
    float v = (d < 32) ? Wq[d * NC + c] : Wk[(d - 32) * NC + c];
    Wcat[i] = f2bf(v);
  }
  for (int i = tid; i < NC * NC; i += nt) Wvb[i] = f2bf(Wv[i]);
  for (int i = tid; i < 1024; i += nt) stats[i] = 0.f;
}

// ---------------------------------------------------------------------------
// K1: xbf[b][c][n] = bf16(x); xT[b][n][c] = bf16(x) transposed (LDS 64x64 tile)
__global__ __launch_bounds__(256) void k1_cvt_tr(const float* __restrict__ x,
                                                 unsigned short* __restrict__ xbf,
                                                 unsigned short* __restrict__ xT) {
  __shared__ __align__(16) unsigned short lt[64][68];
  int bid = blockIdx.x;            // b*256 + cb*64 + nb
  int b  = bid >> 8;
  int cb = (bid >> 6) & 3;
  int nb = bid & 63;
  int c0 = cb * 64, n0 = nb * 64;
  int t = threadIdx.x;
  int tc = t >> 4;                 // 0..15
  int tn = (t & 15) * 4;           // 0..60
#pragma unroll
  for (int it = 0; it < 4; ++it) {
    int c = c0 + tc + it * 16;
    f32x4 xv = *reinterpret_cast<const f32x4*>(&x[((size_t)b * NC + c) * NN + n0 + tn]);
    u16x4 hv;
    hv[0] = f2bf(xv[0]); hv[1] = f2bf(xv[1]); hv[2] = f2bf(xv[2]); hv[3] = f2bf(xv[3]);
    *reinterpret_cast<u16x4*>(&xbf[((size_t)b * NC + c) * NN + n0 + tn]) = hv;
    *reinterpret_cast<u16x4*>(&lt[tc + it * 16][tn]) = hv;
  }
  __syncthreads();
  int nl = t >> 2;                 // 0..63
  int cl0 = (t & 3) * 16;          // 0..48
  u16x8 o0, o1;
#pragma unroll
  for (int q = 0; q < 8; ++q) o0[q] = lt[cl0 + q][nl];
#pragma unroll
  for (int q = 0; q < 8; ++q) o1[q] = lt[cl0 + 8 + q][nl];
  size_t ro = ((size_t)b * NN + n0 + nl) * NC + c0 + cl0;
  *reinterpret_cast<u16x8*>(&xT[ro]) = o0;
  *reinterpret_cast<u16x8*>(&xT[ro + 8]) = o1;
}

// ---------------------------------------------------------------------------
// K2: Qt[b][i][0..31] (bf16, PRE-SCALED by log2e), Kt[b][i][0..31] (bf16)
__global__ __launch_bounds__(256, 2) void k2_qk(const unsigned short* __restrict__ xT,
                                                const unsigned short* __restrict__ Wcat,
                                                const float* __restrict__ bq,
                                                const float* __restrict__ bk,
                                                unsigned short* __restrict__ Qt,
                                                unsigned short* __restrict__ Kt) {
  __shared__ __align__(16) unsigned short lt2[64][72];
  int bid = blockIdx.x;            // b*64 + it
  int b = bid >> 6, it = bid & 63;
  int i0 = it * 64;
  int t = threadIdx.x;
  int w = t >> 6, l = t & 63, l15 = l & 15, g = l >> 4;

  f32x4 acc[4];
#pragma unroll
  for (int f = 0; f < 4; ++f) acc[f] = f32x4{0.f, 0.f, 0.f, 0.f};

  const unsigned short* xrow = &xT[((size_t)b * NN + i0 + w * 16 + l15) * NC];
#pragma unroll
  for (int ks = 0; ks < 8; ++ks) {
    bf16x8 a = *reinterpret_cast<const bf16x8*>(&xrow[ks * 32 + g * 8]);
#pragma unroll
    for (int f = 0; f < 4; ++f) {
      bf16x8 bb = *reinterpret_cast<const bf16x8*>(&Wcat[(f * 16 + l15) * NC + ks * 32 + g * 8]);
      acc[f] = __builtin_amdgcn_mfma_f32_16x16x32_bf16(a, bb, acc[f], 0, 0, 0);
    }
  }
#pragma unroll
  for (int f = 0; f < 4; ++f) {
    int d = f * 16 + l15;
    float bias = (f < 2) ? bq[d] : bk[d - 32];
    float scale = (f < 2) ? LOG2E : 1.0f;     // fold exp->exp2 into Q
#pragma unroll
    for (int r = 0; r < 4; ++r)
      lt2[w * 16 + g * 4 + r][d] = f2bf((acc[f][r] + bias) * scale);
  }
  __syncthreads();
  int il = t >> 2, quad = t & 3;
  u32x4 v0 = *reinterpret_cast<const u32x4*>(&lt2[il][quad * 16]);
  u32x4 v1 = *reinterpret_cast<const u32x4*>(&lt2[il][quad * 16 + 8]);
  unsigned short* dst = (quad < 2) ? &Qt[((size_t)b * NN + i0 + il) * 32 + quad * 16]
                                   : &Kt[((size_t)b * NN + i0 + il) * 32 + (quad - 2) * 16];
  *reinterpret_cast<u32x4*>(dst) = v0;
  *reinterpret_cast<u32x4*>(&dst[8]) = v1;
}

// ---------------------------------------------------------------------------
// K3: Lrow[b][i] = -log2( sum_j exp2(S'[i,j]) ).  Block = 16 i-rows.
__global__ __launch_bounds__(256, 4) void k3_rowsum(const unsigned short* __restrict__ Qt,
                                                    const unsigned short* __restrict__ Kt,
                                                    float* __restrict__ Lrow) {
  __shared__ float sred[4][16];
  int bid = blockIdx.x;            // b*256 + it16
  int b = bid >> 8, it = bid & 255;
  int i0 = it * 16;
  int t = threadIdx.x, w = t >> 6, l = t & 63, l15 = l & 15, g = l >> 4;
  bf16x8 a = *reinterpret_cast<const bf16x8*>(&Qt[((size_t)b * NN + i0 + l15) * 32 + g * 8]);
  float rs0 = 0.f, rs1 = 0.f, rs2 = 0.f, rs3 = 0.f;
  int jbase = w * 1024;
  for (int jc = 0; jc < 16; ++jc) {
    int jb = jbase + jc * 64;
#pragma unroll
    for (int f = 0; f < 4; ++f) {
      bf16x8 bb = *reinterpret_cast<const bf16x8*>(&Kt[((size_t)b * NN + jb + f * 16 + l15) * 32 + g * 8]);
      f32x4 s = __builtin_amdgcn_mfma_f32_16x16x32_bf16(a, bb, f32x4{0.f, 0.f, 0.f, 0.f}, 0, 0, 0);
      rs0 += EXP2(s[0]); rs1 += EXP2(s[1]); rs2 += EXP2(s[2]); rs3 += EXP2(s[3]);
    }
  }
#pragma unroll
  for (int m = 1; m < 16; m <<= 1) {
    rs0 += __shfl_xor(rs0, m); rs1 += __shfl_xor(rs1, m);
    rs2 += __shfl_xor(rs2, m); rs3 += __shfl_xor(rs3, m);
  }
  if (l15 == 0) {
    sred[w][g * 4 + 0] = rs0; sred[w][g * 4 + 1] = rs1;
    sred[w][g * 4 + 2] = rs2; sred[w][g * 4 + 3] = rs3;
  }
  __syncthreads();
  if (t < 16) {
    float d = sred[0][t] + sred[1][t] + sred[2][t] + sred[3][t];
    Lrow[(size_t)b * NN + i0 + t] = -__log2f(d);   // P = exp2(S' + L)
  }
}

// ---------------------------------------------------------------------------
// K4: fused attention*V-contraction, ZERO LDS / ZERO barriers.
// 32x32x16 MFMAs. S-acc C-init = Lrow[i] broadcast -> exp2 gives P directly.
// P D-frag -> T B-frag via pack(bf16 pairs) + permlane32_swap (T12 pattern).
// Block: bid&1=ih, (bid>>1)&3=b, bid>>3=jt (XCD gets one (b,ih) slice).
// 4 waves: jw=w>>1 (j 32 each), cw=w&1 (c 128 each). 64 i-iters of 32.
__global__ __launch_bounds__(256, 2) void k4_attn(const unsigned short* __restrict__ xbf,
                                                  const unsigned short* __restrict__ Qt,
                                                  const unsigned short* __restrict__ Kt,
                                                  const float* __restrict__ Lrow,
                                                  unsigned short* __restrict__ Tt,
                                                  float* __restrict__ scol) {
  int bid = blockIdx.x;
  int ih = bid & 1;
  int b  = (bid >> 1) & 3;
  int jt = bid >> 3;
  int t = threadIdx.x, w = t >> 6;
  int jw = w >> 1, cw = w & 1;
  int l = t & 63, l31 = l & 31, h = l >> 5;
  int j0 = jt * 64 + jw * 32;
  int c0 = cw * 128;
  const size_t qbase = (size_t)b * NN;
  unsigned short* Tt_p = Tt + (size_t)ih * ((size_t)NB * NN * NC);
  float* scol_p = scol + (size_t)ih * (NB * NN);
  int i0base = ih * 2048;

  // hoisted K fragments (B-operand: lane = row j, k-slice d)
  bf16x8 bk0 = *reinterpret_cast<const bf16x8*>(&Kt[(qbase + j0 + l31) * 32 + h * 8]);
  bf16x8 bk1 = *reinterpret_cast<const bf16x8*>(&Kt[(qbase + j0 + l31) * 32 + 16 + h * 8]);

  f32x16 acc0 = {0}, acc1 = {0}, acc2 = {0}, acc3 = {0};
  float cs = 0.f;

  for (int ic = 0; ic < 64; ++ic) {
    int ibase = i0base + ic * 32;
    // C-init: L[i] broadcast across j. D row i = (r&3)+8*(r>>2)+4h.
    const float* Lb = &Lrow[qbase + ibase + 4 * h];
    f32x4 l0 = *reinterpret_cast<const f32x4*>(&Lb[0]);
    f32x4 l1 = *reinterpret_cast<const f32x4*>(&Lb[8]);
    f32x4 l2 = *reinterpret_cast<const f32x4*>(&Lb[16]);
    f32x4 l3 = *reinterpret_cast<const f32x4*>(&Lb[24]);
    f32x16 s;
#pragma unroll
    for (int r = 0; r < 4; ++r) { s[r] = l0[r]; s[4 + r] = l1[r]; s[8 + r] = l2[r]; s[12 + r] = l3[r]; }
    // S = Q.K^T + L  (A: lane = row i, k-slice d)
    bf16x8 aq0 = *reinterpret_cast<const bf16x8*>(&Qt[(qbase + ibase + l31) * 32 + h * 8]);
    bf16x8 aq1 = *reinterpret_cast<const bf16x8*>(&Qt[(qbase + ibase + l31) * 32 + 16 + h * 8]);
    s = __builtin_amdgcn_mfma_f32_32x32x16_bf16(aq0, bk0, s, 0, 0, 0);
    s = __builtin_amdgcn_mfma_f32_32x32x16_bf16(aq1, bk1, s, 0, 0, 0);
    // P = exp2(S)  (<=1 by construction); colsum accumulate
    float p[16];
#pragma unroll
    for (int r = 0; r < 16; ++r) { p[r] = EXP2(s[r]); cs += p[r]; }
    // pack c-pairs -> 8 u32 of 2 bf16; swap halves -> B-frags for both k-blocks
    unsigned q[8];
#pragma unroll
    for (int k = 0; k < 8; ++k)
      q[k] = (unsigned)f2bf(p[2 * k]) | ((unsigned)f2bf(p[2 * k + 1]) << 16);
    u32x2 s02 = lane32swap(q[0], q[2]);
    u32x2 s13 = lane32swap(q[1], q[3]);
    u32x2 s46 = lane32swap(q[4], q[6]);
    u32x2 s57 = lane32swap(q[5], q[7]);
    union { u32x4 u; bf16x8 v; } bm0, bm1;
    bm0.u = u32x4{s02[0], s13[0], s02[1], s13[1]};   // P rows i in [ibase, ibase+16)
    bm1.u = u32x4{s46[0], s57[0], s46[1], s57[1]};   // P rows i in [ibase+16, +32)
    // T[c][j] += x[c][i] * P[i][j]
    const size_t xrow = (size_t)b * NC + c0;
#pragma unroll
    for (int m = 0; m < 2; ++m) {
      bf16x8 bp = m ? bm1.v : bm0.v;
      int io = ibase + m * 16 + h * 8;
      bf16x8 ax0 = *reinterpret_cast<const bf16x8*>(&xbf[(xrow + 0  + l31) * NN + io]);
      bf16x8 ax1 = *reinterpret_cast<const bf16x8*>(&xbf[(xrow + 32 + l31) * NN + io]);
      bf16x8 ax2 = *reinterpret_cast<const bf16x8*>(&xbf[(xrow + 64 + l31) * NN + io]);
      bf16x8 ax3 = *reinterpret_cast<const bf16x8*>(&xbf[(xrow + 96 + l31) * NN + io]);
      acc0 = __builtin_amdgcn_mfma_f32_32x32x16_bf16(ax0, bp, acc0, 0, 0, 0);
      acc1 = __builtin_amdgcn_mfma_f32_32x32x16_bf16(ax1, bp, acc1, 0, 0, 0);
      acc2 = __builtin_amdgcn_mfma_f32_32x32x16_bf16(ax2, bp, acc2, 0, 0, 0);
      acc3 = __builtin_amdgcn_mfma_f32_32x32x16_bf16(ax3, bp, acc3, 0, 0, 0);
    }
  }
  // colsum: add the two halves (each lane summed its 16 i-rows for col j)
  cs += __shfl_xor(cs, 32);
  if (cw == 0 && l < 32) scol_p[qbase + j0 + l] = cs;
  // Tt store: same pack+swap -> lane holds 8 consecutive c per 16-c block
#pragma unroll
  for (int ci = 0; ci < 4; ++ci) {
    f32x16 a = (ci == 0) ? acc0 : (ci == 1) ? acc1 : (ci == 2) ? acc2 : acc3;
    unsigned qq[8];
#pragma unroll
    for (int k = 0; k < 8; ++k)
      qq[k] = (unsigned)f2bf(a[2 * k]) | ((unsigned)f2bf(a[2 * k + 1]) << 16);
    u32x2 t02 = lane32swap(qq[0], qq[2]);
    u32x2 t13 = lane32swap(qq[1], qq[3]);
    u32x2 t46 = lane32swap(qq[4], qq[6]);
    u32x2 t57 = lane32swap(qq[5], qq[7]);
    size_t row = (qbase + j0 + l31) * NC + c0 + ci * 32 + 8 * h;
    *reinterpret_cast<u32x4*>(&Tt_p[row])      = u32x4{t02[0], t13[0], t02[1], t13[1]};
    *reinterpret_cast<u32x4*>(&Tt_p[row + 16]) = u32x4{t46[0], t57[0], t46[1], t57[1]};
  }
}

// ---------------------------------------------------------------------------
// K5: out[c,j] = sum_c' Wv[c,c'] * (T0+T1)[c',j] + bv[c]*(s0+s1)[j]  (pure GEMM)
__global__ __launch_bounds__(256, 2) void k5_out(const unsigned short* __restrict__ Wvb,
                                                 const unsigned short* __restrict__ Tt,
                                                 const float* __restrict__ scol,
                                                 const float* __restrict__ bv,
                                                 unsigned short* __restrict__ outbf) {
  int bid = blockIdx.x;            // b*128 + jt
  int b = bid >> 7, jt = bid & 127;
  int j0 = jt * 32;
  int t = threadIdx.x, w = t >> 6, l = t & 63, l15 = l & 15, g = l >> 4;
  f32x4 acc[4][2];
#pragma unroll
  for (int ci = 0; ci < 4; ++ci)
#pragma unroll
    for (int f = 0; f < 2; ++f) acc[ci][f] = f32x4{0.f, 0.f, 0.f, 0.f};

#pragma unroll
  for (int ks = 0; ks < 8; ++ks) {
    bf16x8 a[4];
#pragma unroll
    for (int ci = 0; ci < 4; ++ci)
      a[ci] = *reinterpret_cast<const bf16x8*>(&Wvb[(w * 64 + ci * 16 + l15) * NC + ks * 32 + g * 8]);
#pragma unroll
    for (int h = 0; h < 2; ++h) {
      const unsigned short* T = Tt + (size_t)h * ((size_t)NB * NN * NC);
      bf16x8 bb[2];
#pragma unroll
      for (int f = 0; f < 2; ++f)
        bb[f] = *reinterpret_cast<const bf16x8*>(&T[((size_t)b * NN + j0 + f * 16 + l15) * NC + ks * 32 + g * 8]);
#pragma unroll
      for (int ci = 0; ci < 4; ++ci) {
        acc[ci][0] = __builtin_amdgcn_mfma_f32_16x16x32_bf16(a[ci], bb[0], acc[ci][0], 0, 0, 0);
        acc[ci][1] = __builtin_amdgcn_mfma_f32_16x16x32_bf16(a[ci], bb[1], acc[ci][1], 0, 0, 0);
      }
    }
  }
  float sv[2];
#pragma unroll
  for (int f = 0; f < 2; ++f) {
    size_t ji = (size_t)b * NN + j0 + f * 16 + l15;
    sv[f] = scol[ji] + scol[(size_t)NB * NN + ji];
  }
#pragma unroll
  for (int ci = 0; ci < 4; ++ci) {
    f32x4 bv4 = *reinterpret_cast<const f32x4*>(&bv[w * 64 + ci * 16 + g * 4]);
#pragma unroll
    for (int r = 0; r < 4; ++r) {
      int c = w * 64 + ci * 16 + g * 4 + r;
#pragma unroll
      for (int f = 0; f < 2; ++f)
        outbf[((size_t)b * NC + c) * NN + j0 + f * 16 + l15] = f2bf(acc[ci][f][r] + bv4[r] * sv[f]);
    }
  }
}

// ---------------------------------------------------------------------------
// K5a: BN partial stats from outbf: stats[c] += sum, stats[256+c] += sumsq
__global__ __launch_bounds__(256) void k5a_stats(const unsigned short* __restrict__ outbf,
                                                 float* __restrict__ stats) {
  __shared__ float sred[2][4];
  int c = blockIdx.x >> 1, half = blockIdx.x & 1;
  int t = threadIdx.x;
  float sum = 0.f, sq = 0.f;
#pragma unroll
  for (int b = 0; b < 4; ++b) {
    u16x8 v = *reinterpret_cast<const u16x8*>(
        &outbf[((((size_t)b << 8) + c) << 12) + half * 2048 + t * 8]);
#pragma unroll
    for (int q = 0; q < 8; ++q) {
      float f = bf2f(v[q]);
      sum += f; sq = fmaf(f, f, sq);
    }
  }
#pragma unroll
  for (int m = 1; m < 64; m <<= 1) {
    sum += __shfl_xor(sum, m); sq += __shfl_xor(sq, m);
  }
  if ((t & 63) == 0) { sred[0][t >> 6] = sum; sred[1][t >> 6] = sq; }
  __syncthreads();
  if (t == 0) {
    atomicAdd(&stats[c],       sred[0][0] + sred[0][1] + sred[0][2] + sred[0][3]);
    atomicAdd(&stats[256 + c], sred[1][0] + sred[1][1] + sred[1][2] + sred[1][3]);
  }
}

// ---------------------------------------------------------------------------
// K6: finalize BN -> per-channel scale/shift (x1e-5 folded)
__global__ __launch_bounds__(256) void k6_fin(const float* __restrict__ gamma,
                                              const float* __restrict__ beta,
                                              float* __restrict__ stats) {
  int c = threadIdx.x;
  float mean = stats[c] * (1.0f / 16384.0f);
  float var = stats[256 + c] * (1.0f / 16384.0f) - mean * mean;
  float rstd = rsqrtf(var + 1e-5f);
  float sc = gamma[c] * rstd;
  stats[512 + c] = sc * 1e-5f;
  stats[768 + c] = (beta[c] - mean * sc) * 1e-5f;
}

// ---------------------------------------------------------------------------
// K7: y = x + outbf*scale[c] + shift[c]
__global__ __launch_bounds__(256) void k7_final(const float* __restrict__ x,
                                                const unsigned short* __restrict__ outbf,
                                                const float* __restrict__ stats,
                                                float* __restrict__ y) {
  int tid = blockIdx.x * 256 + threadIdx.x;
  size_t base = (size_t)tid * 8;
  int c = (int)((base >> 12) & 255);
  float sc = stats[512 + c], sh = stats[768 + c];
  u16x8 ov = *reinterpret_cast<const u16x8*>(&outbf[base]);
  f32x4 x0 = *reinterpret_cast<const f32x4*>(&x[base]);
  f32x4 x1 = *reinterpret_cast<const f32x4*>(&x[base + 4]);
  f32x4 y0, y1;
#pragma unroll
  for (int q = 0; q < 4; ++q) y0[q] = x0[q] + bf2f(ov[q]) * sc + sh;
#pragma unroll
  for (int q = 0; q < 4; ++q) y1[q] = x1[q] + bf2f(ov[4 + q]) * sc + sh;
  *reinterpret_cast<f32x4*>(&y[base]) = y0;
  *reinterpret_cast<f32x4*>(&y[base + 4]) = y1;
}

// ---------------------------------------------------------------------------
extern "C" void kernel_launch(void* const* d_in, const int* in_sizes, int n_in,
                              void* d_out, int out_size, void* d_ws, size_t ws_size,
                              hipStream_t stream) {
  (void)in_sizes; (void)n_in; (void)out_size;
  if (ws_size < 27627520) return;  // workspace layout requires ~26.4 MB

  const float* x    = (const float*)d_in[0];
  const float* Wq   = (const float*)d_in[1];
  const float* bq   = (const float*)d_in[2];
  const float* Wk   = (const float*)d_in[3];
  const float* bk   = (const float*)d_in[4];
  const float* Wv   = (const float*)d_in[5];
  const float* bv   = (const float*)d_in[6];
  const float* gam  = (const float*)d_in[7];
  const float* bet  = (const float*)d_in[8];
  float* y = (float*)d_out;
  char* ws = (char*)d_ws;

  unsigned short* xbf  = (unsigned short*)(ws + 0);          // 8 MB; reused as outbf
  unsigned short* Tt   = (unsigned short*)(ws + 8388608);    // 2 x 8 MB; first 8MB doubles as xT for K2
  unsigned short* Qt   = (unsigned short*)(ws + 25165824);   // 1 MB
  unsigned short* Kt   = (unsigned short*)(ws + 26214400);   // 1 MB
  float* Lrow          = (float*)(ws + 27262976);            // 64 KB
  float* scol          = (float*)(ws + 27328512);            // 2 x 64 KB
  float* stats         = (float*)(ws + 27459584);            // 4 KB
  unsigned short* Wcat = (unsigned short*)(ws + 27463680);   // 32 KB
  unsigned short* Wvb  = (unsigned short*)(ws + 27496448);   // 128 KB
  unsigned short* xT   = Tt;       // k2 input; overwritten by k4 as Tt[0]
  unsigned short* outbf = xbf;     // k5 output; xbf dead after k4

  hipLaunchKernelGGL(k0_prep,  dim3(256),  dim3(256), 0, stream, Wq, Wk, Wv, Wcat, Wvb, stats);
  hipLaunchKernelGGL(k1_cvt_tr,dim3(1024), dim3(256), 0, stream, x, xbf, xT);
  hipLaunchKernelGGL(k2_qk,    dim3(256),  dim3(256), 0, stream, xT, Wcat, bq, bk, Qt, Kt);
  hipLaunchKernelGGL(k3_rowsum,dim3(1024), dim3(256), 0, stream, Qt, Kt, Lrow);
  hipLaunchKernelGGL(k4_attn,  dim3(512),  dim3(256), 0, stream, xbf, Qt, Kt, Lrow, Tt, scol);
  hipLaunchKernelGGL(k5_out,   dim3(512),  dim3(256), 0, stream, Wvb, Tt, scol, bv, outbf);
  hipLaunchKernelGGL(k5a_stats,dim3(512),  dim3(256), 0, stream, outbf, stats);
  hipLaunchKernelGGL(k6_fin,   dim3(1),    dim3(256), 0, stream, gam, bet, stats);
  hipLaunchKernelGGL(k7_final, dim3(2048), dim3(256), 0, stream, x, outbf, stats, y);
}

// Round 7
// 206.754 us; speedup vs baseline: 1.3839x; 1.3839x over previous
//
#include <hip/hip_runtime.h>
#include <hip/hip_bf16.h>

// Problem constants
#define NB 4
#define NC 256
#define NN 4096   // H*W
// DQK = 32

typedef __bf16 bf16x8 __attribute__((ext_vector_type(8)));
typedef float f32x4 __attribute__((ext_vector_type(4)));
typedef float f32x16 __attribute__((ext_vector_type(16)));
typedef unsigned short u16x4 __attribute__((ext_vector_type(4)));
typedef unsigned short u16x8 __attribute__((ext_vector_type(8)));
typedef unsigned int u32x2 __attribute__((ext_vector_type(2)));
typedef unsigned int u32x4 __attribute__((ext_vector_type(4)));

#if __has_builtin(__builtin_amdgcn_exp2f)
#define EXP2(x) __builtin_amdgcn_exp2f(x)
#else
#define EXP2(x) exp2f(x)
#endif

#define LOG2E 1.4426950408889634f

__device__ __forceinline__ unsigned short f2bf(float f) {
  union { __bf16 h; unsigned short u; } v;
  v.h = (__bf16)f;               // native v_cvt (RNE) on gfx950
  return v.u;
}
__device__ __forceinline__ float bf2f(unsigned short h) {
  union { unsigned u; float f; } v; v.u = ((unsigned)h) << 16;
  return v.f;
}

// permlane32_swap wrapper (verified passing in round 4)
__device__ __forceinline__ u32x2 lane32swap(unsigned a, unsigned b) {
#if __has_builtin(__builtin_amdgcn_permlane32_swap)
  return __builtin_amdgcn_permlane32_swap(a, b, false, false);
#else
  unsigned ca = __shfl_xor(a, 32), cb = __shfl_xor(b, 32);
  int h = (threadIdx.x & 63) >> 5;
  u32x2 r; r[0] = h ? cb : a; r[1] = h ? b : ca;
  return r;
#endif
}

// ---------------------------------------------------------------------------
// K0: weights -> bf16 (Wcat = [Wq;Wk] 64x256, Wvb 256x256), zero stats buffer
__global__ __launch_bounds__(256) void k0_prep(const float* __restrict__ Wq,
                                               const float* __restrict__ Wk,
                                               const float* __restrict__ Wv,
                                               unsigned short* __restrict__ Wcat,
                                               unsigned short* __restrict__ Wvb,
                                               float* __restrict__ stats) {
  int tid = blockIdx.x * 256 + threadIdx.x;
  int nt = gridDim.x * 256;
  for (int i = tid; i < 64 * NC; i += nt) {
    int d = i >> 8, c = i & 255;
    float v = (d < 32) ? Wq[d * NC + c] : Wk[(d - 32) * NC + c];
    Wcat[i] = f2bf(v);
  }
  for (int i = tid; i < NC * NC; i += nt) Wvb[i] = f2bf(Wv[i]);
  for (int i = tid; i < 1024; i += nt) stats[i] = 0.f;
}

// ---------------------------------------------------------------------------
// K1: xbf[b][c][n] = bf16(x); xT[b][n][c] = bf16(x) transposed (LDS 64x64 tile)
__global__ __launch_bounds__(256) void k1_cvt_tr(const float* __restrict__ x,
                                                 unsigned short* __restrict__ xbf,
                                                 unsigned short* __restrict__ xT) {
  __shared__ __align__(16) unsigned short lt[64][68];
  int bid = blockIdx.x;            // b*256 + cb*64 + nb
  int b  = bid >> 8;
  int cb = (bid >> 6) & 3;
  int nb = bid & 63;
  int c0 = cb * 64, n0 = nb * 64;
  int t = threadIdx.x;
  int tc = t >> 4;                 // 0..15
  int tn = (t & 15) * 4;           // 0..60
#pragma unroll
  for (int it = 0; it < 4; ++it) {
    int c = c0 + tc + it * 16;
    f32x4 xv = *reinterpret_cast<const f32x4*>(&x[((size_t)b * NC + c) * NN + n0 + tn]);
    u16x4 hv;
    hv[0] = f2bf(xv[0]); hv[1] = f2bf(xv[1]); hv[2] = f2bf(xv[2]); hv[3] = f2bf(xv[3]);
    *reinterpret_cast<u16x4*>(&xbf[((size_t)b * NC + c) * NN + n0 + tn]) = hv;
    *reinterpret_cast<u16x4*>(&lt[tc + it * 16][tn]) = hv;
  }
  __syncthreads();
  int nl = t >> 2;                 // 0..63
  int cl0 = (t & 3) * 16;          // 0..48
  u16x8 o0, o1;
#pragma unroll
  for (int q = 0; q < 8; ++q) o0[q] = lt[cl0 + q][nl];
#pragma unroll
  for (int q = 0; q < 8; ++q) o1[q] = lt[cl0 + 8 + q][nl];
  size_t ro = ((size_t)b * NN + n0 + nl) * NC + c0 + cl0;
  *reinterpret_cast<u16x8*>(&xT[ro]) = o0;
  *reinterpret_cast<u16x8*>(&xT[ro + 8]) = o1;
}

// ---------------------------------------------------------------------------
// K2: Qt[b][i][0..31] (bf16, PRE-SCALED by log2e), Kt[b][i][0..31] (bf16)
__global__ __launch_bounds__(256, 2) void k2_qk(const unsigned short* __restrict__ xT,
                                                const unsigned short* __restrict__ Wcat,
                                                const float* __restrict__ bq,
                                                const float* __restrict__ bk,
                                                unsigned short* __restrict__ Qt,
                                                unsigned short* __restrict__ Kt) {
  __shared__ __align__(16) unsigned short lt2[64][72];
  int bid = blockIdx.x;            // b*64 + it
  int b = bid >> 6, it = bid & 63;
  int i0 = it * 64;
  int t = threadIdx.x;
  int w = t >> 6, l = t & 63, l15 = l & 15, g = l >> 4;

  f32x4 acc[4];
#pragma unroll
  for (int f = 0; f < 4; ++f) acc[f] = f32x4{0.f, 0.f, 0.f, 0.f};

  const unsigned short* xrow = &xT[((size_t)b * NN + i0 + w * 16 + l15) * NC];
#pragma unroll
  for (int ks = 0; ks < 8; ++ks) {
    bf16x8 a = *reinterpret_cast<const bf16x8*>(&xrow[ks * 32 + g * 8]);
#pragma unroll
    for (int f = 0; f < 4; ++f) {
      bf16x8 bb = *reinterpret_cast<const bf16x8*>(&Wcat[(f * 16 + l15) * NC + ks * 32 + g * 8]);
      acc[f] = __builtin_amdgcn_mfma_f32_16x16x32_bf16(a, bb, acc[f], 0, 0, 0);
    }
  }
#pragma unroll
  for (int f = 0; f < 4; ++f) {
    int d = f * 16 + l15;
    float bias = (f < 2) ? bq[d] : bk[d - 32];
    float scale = (f < 2) ? LOG2E : 1.0f;     // fold exp->exp2 into Q
#pragma unroll
    for (int r = 0; r < 4; ++r)
      lt2[w * 16 + g * 4 + r][d] = f2bf((acc[f][r] + bias) * scale);
  }
  __syncthreads();
  int il = t >> 2, quad = t & 3;
  u32x4 v0 = *reinterpret_cast<const u32x4*>(&lt2[il][quad * 16]);
  u32x4 v1 = *reinterpret_cast<const u32x4*>(&lt2[il][quad * 16 + 8]);
  unsigned short* dst = (quad < 2) ? &Qt[((size_t)b * NN + i0 + il) * 32 + quad * 16]
                                   : &Kt[((size_t)b * NN + i0 + il) * 32 + (quad - 2) * 16];
  *reinterpret_cast<u32x4*>(dst) = v0;
  *reinterpret_cast<u32x4*>(&dst[8]) = v1;
}

// ---------------------------------------------------------------------------
// K3: Lrow[b][i] = -log2( sum_j exp2(S'[i,j]) ).  Block = 16 i-rows.
__global__ __launch_bounds__(256, 4) void k3_rowsum(const unsigned short* __restrict__ Qt,
                                                    const unsigned short* __restrict__ Kt,
                                                    float* __restrict__ Lrow) {
  __shared__ float sred[4][16];
  int bid = blockIdx.x;            // b*256 + it16
  int b = bid >> 8, it = bid & 255;
  int i0 = it * 16;
  int t = threadIdx.x, w = t >> 6, l = t & 63, l15 = l & 15, g = l >> 4;
  bf16x8 a = *reinterpret_cast<const bf16x8*>(&Qt[((size_t)b * NN + i0 + l15) * 32 + g * 8]);
  float rs0 = 0.f, rs1 = 0.f, rs2 = 0.f, rs3 = 0.f;
  int jbase = w * 1024;
  for (int jc = 0; jc < 16; ++jc) {
    int jb = jbase + jc * 64;
#pragma unroll
    for (int f = 0; f < 4; ++f) {
      bf16x8 bb = *reinterpret_cast<const bf16x8*>(&Kt[((size_t)b * NN + jb + f * 16 + l15) * 32 + g * 8]);
      f32x4 s = __builtin_amdgcn_mfma_f32_16x16x32_bf16(a, bb, f32x4{0.f, 0.f, 0.f, 0.f}, 0, 0, 0);
      rs0 += EXP2(s[0]); rs1 += EXP2(s[1]); rs2 += EXP2(s[2]); rs3 += EXP2(s[3]);
    }
  }
#pragma unroll
  for (int m = 1; m < 16; m <<= 1) {
    rs0 += __shfl_xor(rs0, m); rs1 += __shfl_xor(rs1, m);
    rs2 += __shfl_xor(rs2, m); rs3 += __shfl_xor(rs3, m);
  }
  if (l15 == 0) {
    sred[w][g * 4 + 0] = rs0; sred[w][g * 4 + 1] = rs1;
    sred[w][g * 4 + 2] = rs2; sred[w][g * 4 + 3] = rs3;
  }
  __syncthreads();
  if (t < 16) {
    float d = sred[0][t] + sred[1][t] + sred[2][t] + sred[3][t];
    Lrow[(size_t)b * NN + i0 + t] = -__log2f(d);   // P = exp2(S' + L)
  }
}

// ---------------------------------------------------------------------------
// K4: fused attention*V-contraction. LDS-staged x (coalesced), double-buffered,
// ONE barrier per 64-i stage. In-register P exchange (pack + permlane32_swap).
// LDS layout: 16B granule (c, gi) at granule index G = c*8 + (gi ^ (c&7))
// -> coalesced global reads AND conflict-free ds_read_b128/ds_write_b128.
// Block: bid&1=ih, (bid>>1)&3=b, bid>>3=jt. 4 waves: jw=w>>1 (j 32), cw=w&1 (c 128).
__global__ __launch_bounds__(256, 2) void k4_attn(const unsigned short* __restrict__ xbf,
                                                  const unsigned short* __restrict__ Qt,
                                                  const unsigned short* __restrict__ Kt,
                                                  const float* __restrict__ Lrow,
                                                  unsigned short* __restrict__ Tt,
                                                  float* __restrict__ scol) {
  __shared__ __align__(16) unsigned short xlds[2][16384];  // 2 x 32 KB (256c x 64i)
  int bid = blockIdx.x;
  int ih = bid & 1;
  int b  = (bid >> 1) & 3;
  int jt = bid >> 3;
  int t = threadIdx.x, w = t >> 6;
  int jw = w >> 1, cw = w & 1;
  int l = t & 63, l31 = l & 31, h = l >> 5;
  int j0 = jt * 64 + jw * 32;
  int c0 = cw * 128;
  const size_t qbase = (size_t)b * NN;
  unsigned short* Tt_p = Tt + (size_t)ih * ((size_t)NB * NN * NC);
  float* scol_p = scol + (size_t)ih * (NB * NN);
  int i0base = ih * 2048;
  int crow = t >> 3;               // 0..31 (global c sub-row for staging)
  int slot = t & 7;                // 16B granule within 128B row-chunk

  // hoisted K fragments (B-operand: lane = row j, k-slice d)
  bf16x8 bk0 = *reinterpret_cast<const bf16x8*>(&Kt[(qbase + j0 + l31) * 32 + h * 8]);
  bf16x8 bk1 = *reinterpret_cast<const bf16x8*>(&Kt[(qbase + j0 + l31) * 32 + 16 + h * 8]);

  f32x16 acc0 = {0}, acc1 = {0}, acc2 = {0}, acc3 = {0};
  float cs = 0.f;
  u32x4 sreg0, sreg1, sreg2, sreg3, sreg4, sreg5, sreg6, sreg7;

  // REGLOAD: coalesced 16B/thread x 8: granule (c = q*32+crow, i-gran = slot)
#define REGLOAD(ibase_)                                                              \
  {                                                                                  \
    const unsigned short* xb_ = &xbf[(size_t)b * NC * NN + (ibase_) + slot * 8];     \
    sreg0 = *reinterpret_cast<const u32x4*>(&xb_[(size_t)(0 * 32 + crow) * NN]);     \
    sreg1 = *reinterpret_cast<const u32x4*>(&xb_[(size_t)(1 * 32 + crow) * NN]);     \
    sreg2 = *reinterpret_cast<const u32x4*>(&xb_[(size_t)(2 * 32 + crow) * NN]);     \
    sreg3 = *reinterpret_cast<const u32x4*>(&xb_[(size_t)(3 * 32 + crow) * NN]);     \
    sreg4 = *reinterpret_cast<const u32x4*>(&xb_[(size_t)(4 * 32 + crow) * NN]);     \
    sreg5 = *reinterpret_cast<const u32x4*>(&xb_[(size_t)(5 * 32 + crow) * NN]);     \
    sreg6 = *reinterpret_cast<const u32x4*>(&xb_[(size_t)(6 * 32 + crow) * NN]);     \
    sreg7 = *reinterpret_cast<const u32x4*>(&xb_[(size_t)(7 * 32 + crow) * NN]);     \
  }

  // DSWRITE: swizzled granule G = c*8 + (slot ^ (c&7)); c&7 == crow&7
#define DSWRITE(buf_)                                                                \
  {                                                                                  \
    int gsw_ = (slot ^ (crow & 7)) * 8;                                              \
    unsigned short* lb_ = &xlds[buf_][crow * 64 + gsw_];                             \
    *reinterpret_cast<u32x4*>(&lb_[0 * 2048]) = sreg0;                               \
    *reinterpret_cast<u32x4*>(&lb_[1 * 2048]) = sreg1;                               \
    *reinterpret_cast<u32x4*>(&lb_[2 * 2048]) = sreg2;                               \
    *reinterpret_cast<u32x4*>(&lb_[3 * 2048]) = sreg3;                               \
    *reinterpret_cast<u32x4*>(&lb_[4 * 2048]) = sreg4;                               \
    *reinterpret_cast<u32x4*>(&lb_[5 * 2048]) = sreg5;                               \
    *reinterpret_cast<u32x4*>(&lb_[6 * 2048]) = sreg6;                               \
    *reinterpret_cast<u32x4*>(&lb_[7 * 2048]) = sreg7;                               \
  }
  // note: granule G for (c = q*32+crow) = c*8 + swz = q*256 + crow*8 + swz
  //       -> ushort offset = q*2048 + crow*64 + swz*8  (q stride = 2048)

  REGLOAD(i0base);
  DSWRITE(0);
  __syncthreads();
  int buf = 0;

  for (int st = 0; st < 32; ++st) {
    int ibase = i0base + st * 64;
    if (st + 1 < 32) REGLOAD(ibase + 64);
    const unsigned short* xt = xlds[buf];
#pragma unroll
    for (int ks = 0; ks < 2; ++ks) {
      int isub = ibase + ks * 32;
      // C-init: L[i] broadcast across j. D row i = (r&3)+8*(r>>2)+4h.
      const float* Lb = &Lrow[qbase + isub + 4 * h];
      f32x4 l0 = *reinterpret_cast<const f32x4*>(&Lb[0]);
      f32x4 l1 = *reinterpret_cast<const f32x4*>(&Lb[8]);
      f32x4 l2 = *reinterpret_cast<const f32x4*>(&Lb[16]);
      f32x4 l3 = *reinterpret_cast<const f32x4*>(&Lb[24]);
      f32x16 s;
#pragma unroll
      for (int r = 0; r < 4; ++r) { s[r] = l0[r]; s[4 + r] = l1[r]; s[8 + r] = l2[r]; s[12 + r] = l3[r]; }
      // S = Q.K^T + L
      bf16x8 aq0 = *reinterpret_cast<const bf16x8*>(&Qt[(qbase + isub + l31) * 32 + h * 8]);
      bf16x8 aq1 = *reinterpret_cast<const bf16x8*>(&Qt[(qbase + isub + l31) * 32 + 16 + h * 8]);
      s = __builtin_amdgcn_mfma_f32_32x32x16_bf16(aq0, bk0, s, 0, 0, 0);
      s = __builtin_amdgcn_mfma_f32_32x32x16_bf16(aq1, bk1, s, 0, 0, 0);
      // P = exp2(S); colsum
      float p[16];
#pragma unroll
      for (int r = 0; r < 16; ++r) { p[r] = EXP2(s[r]); cs += p[r]; }
      // pack c-pairs -> bf16x2 words; swap halves -> B-frags for both 16-i blocks
      unsigned q[8];
#pragma unroll
      for (int k = 0; k < 8; ++k)
        q[k] = (unsigned)f2bf(p[2 * k]) | ((unsigned)f2bf(p[2 * k + 1]) << 16);
      u32x2 s02 = lane32swap(q[0], q[2]);
      u32x2 s13 = lane32swap(q[1], q[3]);
      u32x2 s46 = lane32swap(q[4], q[6]);
      u32x2 s57 = lane32swap(q[5], q[7]);
      union { u32x4 u; bf16x8 v; } bm0, bm1;
      bm0.u = u32x4{s02[0], s13[0], s02[1], s13[1]};   // P rows [isub, isub+16)
      bm1.u = u32x4{s46[0], s57[0], s46[1], s57[1]};   // P rows [isub+16, +32)
      // PV from LDS: A-frag (c_loc = c0+ci*32+l31, i_loc = ks*32+m*16+h*8)
      int swl = l31 & 7;
#pragma unroll
      for (int m = 0; m < 2; ++m) {
        bf16x8 bp = m ? bm1.v : bm0.v;
        int gif = ks * 4 + m * 2 + h;
        int gsw = (gif ^ swl) * 8;
        const unsigned short* lr = &xt[(c0 + l31) * 64 + gsw];
        bf16x8 ax0 = *reinterpret_cast<const bf16x8*>(&lr[0 * 2048]);
        bf16x8 ax1 = *reinterpret_cast<const bf16x8*>(&lr[1 * 2048]);
        bf16x8 ax2 = *reinterpret_cast<const bf16x8*>(&lr[2 * 2048]);
        bf16x8 ax3 = *reinterpret_cast<const bf16x8*>(&lr[3 * 2048]);
        acc0 = __builtin_amdgcn_mfma_f32_32x32x16_bf16(ax0, bp, acc0, 0, 0, 0);
        acc1 = __builtin_amdgcn_mfma_f32_32x32x16_bf16(ax1, bp, acc1, 0, 0, 0);
        acc2 = __builtin_amdgcn_mfma_f32_32x32x16_bf16(ax2, bp, acc2, 0, 0, 0);
        acc3 = __builtin_amdgcn_mfma_f32_32x32x16_bf16(ax3, bp, acc3, 0, 0, 0);
      }
      // note: lr rows are 32 c per ci-tile: granule stride per ci = 32*8 = 256
      //       granules -> ushort stride 2048 ✓
    }
    if (st + 1 < 32) DSWRITE(buf ^ 1);
    __syncthreads();
    buf ^= 1;
  }
  // colsum: add the two halves (each lane summed its 16 i-rows for col j)
  cs += __shfl_xor(cs, 32);
  if (cw == 0 && l < 32) scol_p[qbase + j0 + l] = cs;
  // Tt store: pack+swap -> lane holds 8 consecutive c per 16-c block
#pragma unroll
  for (int ci = 0; ci < 4; ++ci) {
    f32x16 a = (ci == 0) ? acc0 : (ci == 1) ? acc1 : (ci == 2) ? acc2 : acc3;
    unsigned qq[8];
#pragma unroll
    for (int k = 0; k < 8; ++k)
      qq[k] = (unsigned)f2bf(a[2 * k]) | ((unsigned)f2bf(a[2 * k + 1]) << 16);
    u32x2 t02 = lane32swap(qq[0], qq[2]);
    u32x2 t13 = lane32swap(qq[1], qq[3]);
    u32x2 t46 = lane32swap(qq[4], qq[6]);
    u32x2 t57 = lane32swap(qq[5], qq[7]);
    size_t row = (qbase + j0 + l31) * NC + c0 + ci * 32 + 8 * h;
    *reinterpret_cast<u32x4*>(&Tt_p[row])      = u32x4{t02[0], t13[0], t02[1], t13[1]};
    *reinterpret_cast<u32x4*>(&Tt_p[row + 16]) = u32x4{t46[0], t57[0], t46[1], t57[1]};
  }
#undef REGLOAD
#undef DSWRITE
}

// ---------------------------------------------------------------------------
// K5: out[c,j] = sum_c' Wv[c,c'] * (T0+T1)[c',j] + bv[c]*(s0+s1)[j]  (pure GEMM)
__global__ __launch_bounds__(256, 2) void k5_out(const unsigned short* __restrict__ Wvb,
                                                 const unsigned short* __restrict__ Tt,
                                                 const float* __restrict__ scol,
                                                 const float* __restrict__ bv,
                                                 unsigned short* __restrict__ outbf) {
  int bid = blockIdx.x;            // b*128 + jt
  int b = bid >> 7, jt = bid & 127;
  int j0 = jt * 32;
  int t = threadIdx.x, w = t >> 6, l = t & 63, l15 = l & 15, g = l >> 4;
  f32x4 acc[4][2];
#pragma unroll
  for (int ci = 0; ci < 4; ++ci)
#pragma unroll
    for (int f = 0; f < 2; ++f) acc[ci][f] = f32x4{0.f, 0.f, 0.f, 0.f};

#pragma unroll
  for (int ks = 0; ks < 8; ++ks) {
    bf16x8 a[4];
#pragma unroll
    for (int ci = 0; ci < 4; ++ci)
      a[ci] = *reinterpret_cast<const bf16x8*>(&Wvb[(w * 64 + ci * 16 + l15) * NC + ks * 32 + g * 8]);
#pragma unroll
    for (int h = 0; h < 2; ++h) {
      const unsigned short* T = Tt + (size_t)h * ((size_t)NB * NN * NC);
      bf16x8 bb[2];
#pragma unroll
      for (int f = 0; f < 2; ++f)
        bb[f] = *reinterpret_cast<const bf16x8*>(&T[((size_t)b * NN + j0 + f * 16 + l15) * NC + ks * 32 + g * 8]);
#pragma unroll
      for (int ci = 0; ci < 4; ++ci) {
        acc[ci][0] = __builtin_amdgcn_mfma_f32_16x16x32_bf16(a[ci], bb[0], acc[ci][0], 0, 0, 0);
        acc[ci][1] = __builtin_amdgcn_mfma_f32_16x16x32_bf16(a[ci], bb[1], acc[ci][1], 0, 0, 0);
      }
    }
  }
  float sv[2];
#pragma unroll
  for (int f = 0; f < 2; ++f) {
    size_t ji = (size_t)b * NN + j0 + f * 16 + l15;
    sv[f] = scol[ji] + scol[(size_t)NB * NN + ji];
  }
#pragma unroll
  for (int ci = 0; ci < 4; ++ci) {
    f32x4 bv4 = *reinterpret_cast<const f32x4*>(&bv[w * 64 + ci * 16 + g * 4]);
#pragma unroll
    for (int r = 0; r < 4; ++r) {
      int c = w * 64 + ci * 16 + g * 4 + r;
#pragma unroll
      for (int f = 0; f < 2; ++f)
        outbf[((size_t)b * NC + c) * NN + j0 + f * 16 + l15] = f2bf(acc[ci][f][r] + bv4[r] * sv[f]);
    }
  }
}

// ---------------------------------------------------------------------------
// K5a: BN partial stats from outbf: stats[c] += sum, stats[256+c] += sumsq
__global__ __launch_bounds__(256) void k5a_stats(const unsigned short* __restrict__ outbf,
                                                 float* __restrict__ stats) {
  __shared__ float sred[2][4];
  int c = blockIdx.x >> 1, half = blockIdx.x & 1;
  int t = threadIdx.x;
  float sum = 0.f, sq = 0.f;
#pragma unroll
  for (int b = 0; b < 4; ++b) {
    u16x8 v = *reinterpret_cast<const u16x8*>(
        &outbf[((((size_t)b << 8) + c) << 12) + half * 2048 + t * 8]);
#pragma unroll
    for (int q = 0; q < 8; ++q) {
      float f = bf2f(v[q]);
      sum += f; sq = fmaf(f, f, sq);
    }
  }
#pragma unroll
  for (int m = 1; m < 64; m <<= 1) {
    sum += __shfl_xor(sum, m); sq += __shfl_xor(sq, m);
  }
  if ((t & 63) == 0) { sred[0][t >> 6] = sum; sred[1][t >> 6] = sq; }
  __syncthreads();
  if (t == 0) {
    atomicAdd(&stats[c],       sred[0][0] + sred[0][1] + sred[0][2] + sred[0][3]);
    atomicAdd(&stats[256 + c], sred[1][0] + sred[1][1] + sred[1][2] + sred[1][3]);
  }
}

// ---------------------------------------------------------------------------
// K6: finalize BN -> per-channel scale/shift (x1e-5 folded)
__global__ __launch_bounds__(256) void k6_fin(const float* __restrict__ gamma,
                                              const float* __restrict__ beta,
                                              float* __restrict__ stats) {
  int c = threadIdx.x;
  float mean = stats[c] * (1.0f / 16384.0f);
  float var = stats[256 + c] * (1.0f / 16384.0f) - mean * mean;
  float rstd = rsqrtf(var + 1e-5f);
  float sc = gamma[c] * rstd;
  stats[512 + c] = sc * 1e-5f;
  stats[768 + c] = (beta[c] - mean * sc) * 1e-5f;
}

// ---------------------------------------------------------------------------
// K7: y = x + outbf*scale[c] + shift[c]
__global__ __launch_bounds__(256) void k7_final(const float* __restrict__ x,
                                                const unsigned short* __restrict__ outbf,
                                                const float* __restrict__ stats,
                                                float* __restrict__ y) {
  int tid = blockIdx.x * 256 + threadIdx.x;
  size_t base = (size_t)tid * 8;
  int c = (int)((base >> 12) & 255);
  float sc = stats[512 + c], sh = stats[768 + c];
  u16x8 ov = *reinterpret_cast<const u16x8*>(&outbf[base]);
  f32x4 x0 = *reinterpret_cast<const f32x4*>(&x[base]);
  f32x4 x1 = *reinterpret_cast<const f32x4*>(&x[base + 4]);
  f32x4 y0, y1;
#pragma unroll
  for (int q = 0; q < 4; ++q) y0[q] = x0[q] + bf2f(ov[q]) * sc + sh;
#pragma unroll
  for (int q = 0; q < 4; ++q) y1[q] = x1[q] + bf2f(ov[4 + q]) * sc + sh;
  *reinterpret_cast<f32x4*>(&y[base]) = y0;
  *reinterpret_cast<f32x4*>(&y[base + 4]) = y1;
}

// ---------------------------------------------------------------------------
extern "C" void kernel_launch(void* const* d_in, const int* in_sizes, int n_in,
                              void* d_out, int out_size, void* d_ws, size_t ws_size,
                              hipStream_t stream) {
  (void)in_sizes; (void)n_in; (void)out_size;
  if (ws_size < 27627520) return;  // workspace layout requires ~26.4 MB

  const float* x    = (const float*)d_in[0];
  const float* Wq   = (const float*)d_in[1];
  const float* bq   = (const float*)d_in[2];
  const float* Wk   = (const float*)d_in[3];
  const float* bk   = (const float*)d_in[4];
  const float* Wv   = (const float*)d_in[5];
  const float* bv   = (const float*)d_in[6];
  const float* gam  = (const float*)d_in[7];
  const float* bet  = (const float*)d_in[8];
  float* y = (float*)d_out;
  char* ws = (char*)d_ws;

  unsigned short* xbf  = (unsigned short*)(ws + 0);          // 8 MB; reused as outbf
  unsigned short* Tt   = (unsigned short*)(ws + 8388608);    // 2 x 8 MB; first 8MB doubles as xT for K2
  unsigned short* Qt   = (unsigned short*)(ws + 25165824);   // 1 MB
  unsigned short* Kt   = (unsigned short*)(ws + 26214400);   // 1 MB
  float* Lrow          = (float*)(ws + 27262976);            // 64 KB
  float* scol          = (float*)(ws + 27328512);            // 2 x 64 KB
  float* stats         = (float*)(ws + 27459584);            // 4 KB
  unsigned short* Wcat = (unsigned short*)(ws + 27463680);   // 32 KB
  unsigned short* Wvb  = (unsigned short*)(ws + 27496448);   // 128 KB
  unsigned short* xT   = Tt;       // k2 input; overwritten by k4 as Tt[0]
  unsigned short* outbf = xbf;     // k5 output; xbf dead after k4

  hipLaunchKernelGGL(k0_prep,  dim3(256),  dim3(256), 0, stream, Wq, Wk, Wv, Wcat, Wvb, stats);
  hipLaunchKernelGGL(k1_cvt_tr,dim3(1024), dim3(256), 0, stream, x, xbf, xT);
  hipLaunchKernelGGL(k2_qk,    dim3(256),  dim3(256), 0, stream, xT, Wcat, bq, bk, Qt, Kt);
  hipLaunchKernelGGL(k3_rowsum,dim3(1024), dim3(256), 0, stream, Qt, Kt, Lrow);
  hipLaunchKernelGGL(k4_attn,  dim3(512),  dim3(256), 0, stream, xbf, Qt, Kt, Lrow, Tt, scol);
  hipLaunchKernelGGL(k5_out,   dim3(512),  dim3(256), 0, stream, Wvb, Tt, scol, bv, outbf);
  hipLaunchKernelGGL(k5a_stats,dim3(512),  dim3(256), 0, stream, outbf, stats);
  hipLaunchKernelGGL(k6_fin,   dim3(1),    dim3(256), 0, stream, gam, bet, stats);
  hipLaunchKernelGGL(k7_final, dim3(2048), dim3(256), 0, stream, x, outbf, stats, y);
}